// Round 5
// baseline (480.857 us; speedup 1.0000x reference)
//
#include <hip/hip_runtime.h>
#include <hip/hip_bf16.h>
#include <stdint.h>

typedef __attribute__((ext_vector_type(8))) short bf16x8;
typedef __attribute__((ext_vector_type(4))) float f32x4;

// Contraction-proof single f32 ops (np emulation must stay unfused).
__device__ __forceinline__ float vmulf(float a, float b) {
    float d; asm volatile("v_mul_f32 %0, %1, %2" : "=v"(d) : "v"(a), "v"(b)); return d;
}
__device__ __forceinline__ float vaddf(float a, float b) {
    float d; asm volatile("v_add_f32 %0, %1, %2" : "=v"(d) : "v"(a), "v"(b)); return d;
}
__device__ __forceinline__ float vsubf(float a, float b) {
    float d; asm volatile("v_sub_f32 %0, %1, %2" : "=v"(d) : "v"(a), "v"(b)); return d;
}

__device__ __forceinline__ short bf16h(float v) {
    __hip_bfloat16 h = __float2bfloat16(v);
    return *(short*)&h;
}
__device__ __forceinline__ float bf16f(short s) {
    return __uint_as_float(((unsigned int)(unsigned short)s) << 16);
}
__device__ __forceinline__ void split2(float v, short& h, short& m) {
    h = bf16h(v);
    m = bf16h(__fsub_rn(v, bf16f(h)));
}

__device__ __forceinline__ float decode_scalar(const void* p, float dflt) {
    float f = *(const float*)p;
    if (!(f == f) || fabsf(f) > 1.0e6f) return dflt;
    return f;
}
__device__ __forceinline__ int decode_ts(const void* p) {
    int w = *(const int*)p;
    if (w >= 1 && w <= 100000) return w;
    return 32;
}

// global->LDS DMA, 16B per lane, zero staging VGPRs. LDS dest is
// wave-uniform base + lane*16 (linear); size must be a literal.
__device__ __forceinline__ void gl16(const float* g, float* l) {
    __builtin_amdgcn_global_load_lds(
        (const __attribute__((address_space(1))) unsigned int*)g,
        (__attribute__((address_space(3))) unsigned int*)l, 16, 0, 0);
}

#define LDA 36   // LDS row stride for the FALLBACK kernels (padded, verified)

// -------- k1a: one BLIS KC=512 panel per block (exact ascending-k chain) ----
// Reference (VERIFIED R17-R19) = AOCL-BLIS zen sgemm: exact KC=512 panels,
// sequential ascending-k IEEE-FMA chain per C element, C = P0 + P1 in order.
// R24: LDS double-buffer + global_load_lds DMA staging (register-prefetch is
//   DEAD: R21 (256,4)-pin -> 6 GB spill; R22 no-pin -> 120 VGPR, 300 MB spill;
//   R23 (256,2) -> 128 VGPR cap, 400 MB spill. hipcc won't hold acc64 +
//   operands + prefetch32.)
// Structure: As/Bs [2][128][32] = exactly 64 KB LDS. global_load_lds writes
//   LINEARLY (lane*16B); bank conflicts on the unpadded 128B rows are fixed
//   by an XOR swizzle applied on BOTH sides (rule T21): LDS slot (r,s) holds
//   elements (s^(r&7))*4..+3 -- achieved by pre-swizzling the per-lane GLOBAL
//   source address (k-independent) -- and reads use col=(g^(row&7))*4.
//   af reads: 4 distinct banksets (g^ty) -> conflict-free; bf: 2-way (free).
// Schedule: stage chunk c+1 into buf^1 right after the barrier, compute
//   chunk c from buf d, one __syncthreads per chunk (drains vmcnt; loads had
//   the whole ~4096-cyc FMA phase to land). 17 barriers vs 32.
// Numerics: same float values at permuted LDS slots; per-element ascending-k
//   FMA chain unchanged -> bit-identical (absmax must stay 0.0078125).
__global__ __launch_bounds__(256) void k1_panel_gemm(
    const float* __restrict__ X,    // [M,K] fp32
    const float* __restrict__ W1,   // [N,K] fp32
    float* __restrict__ P0,         // [M,N] panel-0 out (spikes buffer)
    float* __restrict__ P1,         // [M,N] panel-1 out (workspace)
    int M, int N, int K, int KC)
{
    __shared__ __align__(16) float As[2][128][32];   // 32 KB
    __shared__ __align__(16) float Bs[2][128][32];   // 32 KB

    const int t  = threadIdx.x;
    const int tx = t & 15;
    const int ty = t >> 4;
    const int m0 = blockIdx.x * 128;
    const int n0 = blockIdx.y * 128;
    const int kz = blockIdx.z * KC;
    float* __restrict__ Pout = blockIdx.z ? P1 : P0;

    float p[8][8] = {};   // this panel's sequential chain

    // ---- staging geometry: wave w stages footprints 4w..4w+3 (8 rows each).
    // lane l -> row 8f+(l>>3), slot l&7. Source element offset is the
    // INVERSE swizzle ((l&7)^(l>>3))*4 so that a linear LDS write lands the
    // swizzled layout.
    const int w  = t >> 6;
    const int l  = t & 63;
    const int lr = l >> 3;                  // row within footprint
    const int sw = ((l & 7) ^ lr) << 2;     // pre-swizzled element offset
    size_t ga[4], gb[4];
    #pragma unroll
    for (int c = 0; c < 4; ++c) {
        const int row = ((w << 2) + c) * 8 + lr;       // 0..127, bijective
        ga[c] = (size_t)(m0 + row) * K + sw;
        gb[c] = (size_t)(n0 + row) * K + sw;
    }

    // prologue: stage chunk 0 into buffer 0
    #pragma unroll
    for (int c = 0; c < 4; ++c) {
        const int f = (w << 2) + c;
        gl16(X  + ga[c] + kz, &As[0][f << 3][0]);
        gl16(W1 + gb[c] + kz, &Bs[0][f << 3][0]);
    }
    __syncthreads();

    const int tya = ty & 7;   // read-side XOR (row&7 for af rows ty+16i)
    const int txa = tx & 7;   // read-side XOR (row&7 for bf rows tx+16j)

    int d = 0;
    for (int k0 = kz; k0 < kz + KC; k0 += 32) {
        // stage NEXT chunk into the other buffer (async DMA, no regs)
        const int kn = k0 + 32;
        if (kn < kz + KC) {
            const int dn = d ^ 1;
            #pragma unroll
            for (int c = 0; c < 4; ++c) {
                const int f = (w << 2) + c;
                gl16(X  + ga[c] + kn, &As[dn][f << 3][0]);
                gl16(W1 + gb[c] + kn, &Bs[dn][f << 3][0]);
            }
        }

        // compute chunk from buffer d (swizzled reads)
        #pragma unroll
        for (int g = 0; g < 8; ++g) {
            float4 bfv[8];
            const int cb = (g ^ txa) << 2;
            #pragma unroll
            for (int j = 0; j < 8; ++j)
                bfv[j] = *(const float4*)&Bs[d][tx + 16 * j][cb];
            const int ca = (g ^ tya) << 2;
            #pragma unroll
            for (int i = 0; i < 8; ++i) {
                const float4 af = *(const float4*)&As[d][ty + 16 * i][ca];
                #pragma unroll
                for (int kk = 0; kk < 4; ++kk) {
                    const float a = ((const float*)&af)[kk];
                    #pragma unroll
                    for (int j = 0; j < 8; ++j)
                        p[i][j] = __builtin_fmaf(a, ((const float*)&bfv[j])[kk], p[i][j]);
                }
            }
        }
        __syncthreads();   // drains vmcnt (next chunk landed) + lgkm; swap
        d ^= 1;
    }

    #pragma unroll
    for (int i = 0; i < 8; ++i) {
        const size_t rowb = (size_t)(m0 + ty + 16 * i) * N;
        #pragma unroll
        for (int j = 0; j < 8; ++j)
            Pout[rowb + n0 + tx + 16 * j] = p[i][j];
    }
}

// -------- k1b: fold c = P0 + P1 (BLIS order) + exact f32 asm-unfused scan ---
__global__ __launch_bounds__(256) void k1_combine_scan(
    const float* __restrict__ P0,
    const float* __restrict__ P1,
    const float* __restrict__ b1,
    const void* tau_mem_p, const void* tau_syn_p,
    const void* v_thresh_p, const void* v_reset_p, const void* ts_p,
    float* __restrict__ spikes, int N, int total4)
{
    const int idx4 = blockIdx.x * 256 + threadIdx.x;
    if (idx4 >= total4) return;

    const float tau_m = decode_scalar(tau_mem_p, 10.0f);
    const float tau_s = decode_scalar(tau_syn_p, 5.0f);
    const float vth   = decode_scalar(v_thresh_p, 1.0f);
    const float vrs   = decode_scalar(v_reset_p, 0.0f);
    const int   ts    = decode_ts(ts_p);
    const float rs    = 1.0f / tau_s;
    const float rm    = 1.0f / tau_m;
    const float ivts  = 1.0f / (float)ts;

    const float4 a = ((const float4*)P0)[idx4];
    const float4 b = ((const float4*)P1)[idx4];
    const int col0 = (idx4 * 4) % N;
    const float4 bb = *(const float4*)&b1[col0];

    float cur[4], iv[4], vv[4], cnt[4];
    const float av[4] = {a.x, a.y, a.z, a.w};
    const float bv[4] = {b.x, b.y, b.z, b.w};
    const float bbv[4] = {bb.x, bb.y, bb.z, bb.w};
    #pragma unroll
    for (int e = 0; e < 4; ++e) {
        const float c = vaddf(av[e], bv[e]);         // BLIS fold: P0 + P1
        cur[e] = vmulf(vaddf(c, bbv[e]), ivts);      // exact /32
        iv[e] = 0.0f; vv[e] = 0.0f; cnt[e] = 0.0f;
    }
    for (int tt = 0; tt < ts; ++tt) {
        #pragma unroll
        for (int e = 0; e < 4; ++e) {
            iv[e] = vaddf(vsubf(iv[e], vmulf(rs, iv[e])), cur[e]);
            vv[e] = vaddf(vsubf(vv[e], vmulf(rm, vv[e])), iv[e]);
            const bool s = (vv[e] >= vth);
            cnt[e] += s ? 1.0f : 0.0f;
            vv[e]   = s ? vrs : vv[e];
        }
    }
    ((float4*)spikes)[idx4] = make_float4(cnt[0], cnt[1], cnt[2], cnt[3]);
}

// -------- fallback k1 (R18, verified): used when ws_size is too small -------
__global__ __launch_bounds__(256) void k1_f32chain_snn(
    const float* __restrict__ X, const float* __restrict__ W1,
    const float* __restrict__ b1,
    const void* tau_mem_p, const void* tau_syn_p,
    const void* v_thresh_p, const void* v_reset_p, const void* ts_p,
    float* __restrict__ spikes, int M, int N, int K, int f0)
{
    __shared__ float As[128][LDA];
    __shared__ float Bs[128][LDA];

    const int t  = threadIdx.x;
    const int tx = t & 15;
    const int ty = t >> 4;
    const int m0 = blockIdx.x * 128;
    const int n0 = blockIdx.y * 128;

    float c[8][8] = {};
    float p[8][8] = {};

    for (int k0 = 0; k0 < K; k0 += 32) {
        #pragma unroll
        for (int cc = 0; cc < 4; ++cc) {
            const int li  = cc * 256 + t;
            const int row = li >> 3;
            const int q   = li & 7;
            *(float4*)&As[row][q * 4] =
                *(const float4*)&X[(size_t)(m0 + row) * K + k0 + q * 4];
            *(float4*)&Bs[row][q * 4] =
                *(const float4*)&W1[(size_t)(n0 + row) * K + k0 + q * 4];
        }
        __syncthreads();
        #pragma unroll
        for (int g = 0; g < 8; ++g) {
            float4 af[8], bf[8];
            #pragma unroll
            for (int i = 0; i < 8; ++i)
                af[i] = *(const float4*)&As[ty + 16 * i][g * 4];
            #pragma unroll
            for (int j = 0; j < 8; ++j)
                bf[j] = *(const float4*)&Bs[tx + 16 * j][g * 4];
            #pragma unroll
            for (int kk = 0; kk < 4; ++kk) {
                #pragma unroll
                for (int i = 0; i < 8; ++i) {
                    const float a = ((const float*)&af[i])[kk];
                    #pragma unroll
                    for (int j = 0; j < 8; ++j)
                        p[i][j] = __builtin_fmaf(a, ((const float*)&bf[j])[kk], p[i][j]);
                }
            }
        }
        __syncthreads();
        const int ke = k0 + 32;
        if (ke == f0 || ke == K) {
            #pragma unroll
            for (int i = 0; i < 8; ++i)
                #pragma unroll
                for (int j = 0; j < 8; ++j) {
                    c[i][j] = vaddf(c[i][j], p[i][j]);
                    p[i][j] = 0.0f;
                }
        }
    }

    const float tau_m = decode_scalar(tau_mem_p, 10.0f);
    const float tau_s = decode_scalar(tau_syn_p, 5.0f);
    const float vth   = decode_scalar(v_thresh_p, 1.0f);
    const float vrs   = decode_scalar(v_reset_p, 0.0f);
    const int   ts    = decode_ts(ts_p);
    const float rs    = 1.0f / tau_s;
    const float rm    = 1.0f / tau_m;
    const float ivts  = 1.0f / (float)ts;

    #pragma unroll
    for (int j = 0; j < 8; ++j) {
        const int col    = n0 + tx + 16 * j;
        const float bias = b1[col];
        float cur[8], iv[8], vv[8], cnt[8];
        #pragma unroll
        for (int i = 0; i < 8; ++i) {
            cur[i] = vmulf(vaddf(c[i][j], bias), ivts);
            iv[i] = 0.0f; vv[i] = 0.0f; cnt[i] = 0.0f;
        }
        for (int tt = 0; tt < ts; ++tt) {
            #pragma unroll
            for (int i = 0; i < 8; ++i) {
                iv[i] = vaddf(vsubf(iv[i], vmulf(rs, iv[i])), cur[i]);
                vv[i] = vaddf(vsubf(vv[i], vmulf(rm, vv[i])), iv[i]);
                const bool s = (vv[i] >= vth);
                cnt[i] += s ? 1.0f : 0.0f;
                vv[i]   = s ? vrs : vv[i];
            }
        }
        #pragma unroll
        for (int i = 0; i < 8; ++i)
            spikes[(size_t)(m0 + ty + 16 * i) * N + col] = cnt[i];
    }
}

// -------- k2a: split-K partial GEMM (MFMA bf16-split), no bias --------------
// z selects a KC2=512 k-range; partial -> Pt[z]. 1024 blocks = 4/CU (vs the
// old full-K k2's 256 = 1/CU, which was latency-bound at ~100+ us).
__global__ __launch_bounds__(256) void k2_partial(
    const float* __restrict__ S, const float* __restrict__ W2,
    float* __restrict__ Pt,      // [4][M,N2] partials
    int M, int N2, int K2, int KC2)
{
    __shared__ __align__(16) short Sa[64 * 32];
    __shared__ __align__(16) short Bh[64 * 32];
    __shared__ __align__(16) short Bm[64 * 32];

    const int t    = threadIdx.x;
    const int l    = t & 63;
    const int w    = t >> 6;
    const int quad = l >> 4;
    const int r    = l & 15;
    const int wm   = w & 1;
    const int wn   = w >> 1;

    const int m0 = blockIdx.x * 64;
    const int n0 = blockIdx.y * 64;
    const int kz = blockIdx.z * KC2;
    float* __restrict__ outp = Pt + (size_t)blockIdx.z * M * N2;

    f32x4 acc[2][2] = {};

    for (int k0 = kz; k0 < kz + KC2; k0 += 32) {
        #pragma unroll
        for (int cc = 0; cc < 2; ++cc) {
            const int li  = cc * 256 + t;
            const int row = li >> 3;
            const int q   = li & 7;
            const float4 vs = *(const float4*)&S[(size_t)(m0 + row) * K2 + k0 + q * 4];
            *(short4*)&Sa[row * 32 + q * 4] =
                make_short4(bf16h(vs.x), bf16h(vs.y), bf16h(vs.z), bf16h(vs.w));
            const float4 vb = *(const float4*)&W2[(size_t)(n0 + row) * K2 + k0 + q * 4];
            short h[4], m_[4];
            split2(vb.x, h[0], m_[0]); split2(vb.y, h[1], m_[1]);
            split2(vb.z, h[2], m_[2]); split2(vb.w, h[3], m_[3]);
            *(short4*)&Bh[row * 32 + q * 4] = make_short4(h[0], h[1], h[2], h[3]);
            *(short4*)&Bm[row * 32 + q * 4] = make_short4(m_[0], m_[1], m_[2], m_[3]);
        }
        __syncthreads();

        bf16x8 af[2], bh[2], bm[2];
        #pragma unroll
        for (int i = 0; i < 2; ++i) {
            af[i] = *(const bf16x8*)&Sa[(wm * 32 + i * 16 + r) * 32 + quad * 8];
            bh[i] = *(const bf16x8*)&Bh[(wn * 32 + i * 16 + r) * 32 + quad * 8];
            bm[i] = *(const bf16x8*)&Bm[(wn * 32 + i * 16 + r) * 32 + quad * 8];
        }
        #pragma unroll
        for (int i = 0; i < 2; ++i)
            #pragma unroll
            for (int j = 0; j < 2; ++j) {
                acc[i][j] = __builtin_amdgcn_mfma_f32_16x16x32_bf16(af[i], bh[j], acc[i][j], 0, 0, 0);
                acc[i][j] = __builtin_amdgcn_mfma_f32_16x16x32_bf16(af[i], bm[j], acc[i][j], 0, 0, 0);
            }
        __syncthreads();
    }

    #pragma unroll
    for (int j = 0; j < 2; ++j) {
        const int col = n0 + wn * 32 + j * 16 + r;
        #pragma unroll
        for (int i = 0; i < 2; ++i) {
            const int rowb = m0 + wm * 32 + i * 16 + quad * 4;
            #pragma unroll
            for (int e = 0; e < 4; ++e)
                outp[(size_t)(rowb + e) * N2 + col] = acc[i][j][e];
        }
    }
}

// -------- k2b: out = p0+p1+p2+p3 + b2 ---------------------------------------
__global__ __launch_bounds__(256) void k2_combine(
    const float* __restrict__ Pt, const float* __restrict__ b2,
    float* __restrict__ out, int N2, int total4, size_t stride4)
{
    const int idx4 = blockIdx.x * 256 + threadIdx.x;
    if (idx4 >= total4) return;
    float4 s = ((const float4*)Pt)[idx4];
    #pragma unroll
    for (int z = 1; z < 4; ++z) {
        const float4 v = ((const float4*)Pt)[stride4 * z + idx4];
        s.x += v.x; s.y += v.y; s.z += v.z; s.w += v.w;
    }
    const float4 bb = *(const float4*)&b2[(idx4 * 4) % N2];
    s.x += bb.x; s.y += bb.y; s.z += bb.z; s.w += bb.w;
    ((float4*)out)[idx4] = s;
}

// -------- fallback k2 (verified R4-R19): full-K, bias fused -----------------
__global__ __launch_bounds__(256) void k2_gemm(
    const float* __restrict__ S, const float* __restrict__ W2,
    const float* __restrict__ b2, float* __restrict__ out,
    int M, int N2, int K2)
{
    __shared__ __align__(16) short Sa[64 * 32];
    __shared__ __align__(16) short Bh[64 * 32];
    __shared__ __align__(16) short Bm[64 * 32];

    const int t    = threadIdx.x;
    const int l    = t & 63;
    const int w    = t >> 6;
    const int quad = l >> 4;
    const int r    = l & 15;
    const int wm   = w & 1;
    const int wn   = w >> 1;

    const int m0 = blockIdx.x * 64;
    const int n0 = blockIdx.y * 64;

    f32x4 acc[2][2] = {};

    for (int k0 = 0; k0 < K2; k0 += 32) {
        #pragma unroll
        for (int cc = 0; cc < 2; ++cc) {
            const int li  = cc * 256 + t;
            const int row = li >> 3;
            const int q   = li & 7;
            const float4 vs = *(const float4*)&S[(size_t)(m0 + row) * K2 + k0 + q * 4];
            *(short4*)&Sa[row * 32 + q * 4] =
                make_short4(bf16h(vs.x), bf16h(vs.y), bf16h(vs.z), bf16h(vs.w));
            const float4 vb = *(const float4*)&W2[(size_t)(n0 + row) * K2 + k0 + q * 4];
            short h[4], m_[4];
            split2(vb.x, h[0], m_[0]); split2(vb.y, h[1], m_[1]);
            split2(vb.z, h[2], m_[2]); split2(vb.w, h[3], m_[3]);
            *(short4*)&Bh[row * 32 + q * 4] = make_short4(h[0], h[1], h[2], h[3]);
            *(short4*)&Bm[row * 32 + q * 4] = make_short4(m_[0], m_[1], m_[2], m_[3]);
        }
        __syncthreads();

        bf16x8 af[2], bh[2], bm[2];
        #pragma unroll
        for (int i = 0; i < 2; ++i) {
            af[i] = *(const bf16x8*)&Sa[(wm * 32 + i * 16 + r) * 32 + quad * 8];
            bh[i] = *(const bf16x8*)&Bh[(wn * 32 + i * 16 + r) * 32 + quad * 8];
            bm[i] = *(const bf16x8*)&Bm[(wn * 32 + i * 16 + r) * 32 + quad * 8];
        }
        #pragma unroll
        for (int i = 0; i < 2; ++i)
            #pragma unroll
            for (int j = 0; j < 2; ++j) {
                acc[i][j] = __builtin_amdgcn_mfma_f32_16x16x32_bf16(af[i], bh[j], acc[i][j], 0, 0, 0);
                acc[i][j] = __builtin_amdgcn_mfma_f32_16x16x32_bf16(af[i], bm[j], acc[i][j], 0, 0, 0);
            }
        __syncthreads();
    }

    #pragma unroll
    for (int j = 0; j < 2; ++j) {
        const int col = n0 + wn * 32 + j * 16 + r;
        const float bias = b2[col];
        #pragma unroll
        for (int i = 0; i < 2; ++i) {
            const int rowb = m0 + wm * 32 + i * 16 + quad * 4;
            #pragma unroll
            for (int e = 0; e < 4; ++e)
                out[(size_t)(rowb + e) * N2 + col] = __fadd_rn(acc[i][j][e], bias);
        }
    }
}

extern "C" void kernel_launch(void* const* d_in, const int* in_sizes, int n_in,
                              void* d_out, int out_size, void* d_ws, size_t ws_size,
                              hipStream_t stream) {
    (void)n_in; (void)out_size;

    const float* X  = (const float*)d_in[0];
    const float* W1 = (const float*)d_in[1];
    const float* b1 = (const float*)d_in[2];
    const float* W2 = (const float*)d_in[3];
    const float* b2 = (const float*)d_in[4];
    const void* tau_mem = d_in[5];
    const void* tau_syn = d_in[6];
    const void* vth     = d_in[7];
    const void* vrs     = d_in[8];
    const void* ts      = d_in[11];

    const int H   = in_sizes[2];             // 2048
    const int IN  = in_sizes[1] / H;         // 1024
    const int OUT = in_sizes[4];             // 256
    const int B   = in_sizes[0] / IN;        // 4096

    float* out    = (float*)d_out;           // [B, OUT] fp32
    float* spikes = out + (size_t)B * OUT;   // [B, H]  fp32

    const int KC = 512;                      // VERIFIED: AOCL-BLIS zen KC
    const size_t panel_bytes = (size_t)B * H * sizeof(float);
    const bool ws_ok = (IN == 2 * KC) && (ws_size >= panel_bytes) &&
                       ((uintptr_t)d_ws % 16 == 0);

    if (ws_ok) {
        float* P1 = (float*)d_ws;
        dim3 g1(B / 128, H / 128, 2);
        k1_panel_gemm<<<g1, 256, 0, stream>>>(X, W1, spikes, P1, B, H, IN, KC);

        const int total4 = (B * H) / 4;
        k1_combine_scan<<<(total4 + 255) / 256, 256, 0, stream>>>(
            spikes, P1, b1, tau_mem, tau_syn, vth, vrs, ts, spikes, H, total4);
    } else {
        dim3 g1(B / 128, H / 128);
        k1_f32chain_snn<<<g1, 256, 0, stream>>>(X, W1, b1, tau_mem, tau_syn, vth, vrs, ts,
                                                spikes, B, H, IN, KC);
    }

    // k2: split-K z=4 partials into d_ws (free after combine_scan; 16 MB),
    // then tiny combine. Falls back to full-K k2 if ws not usable.
    const int KC2 = 512;
    const size_t k2_part_bytes = 4 * (size_t)B * OUT * sizeof(float);
    if (ws_ok && H == 4 * KC2 && ws_size >= k2_part_bytes) {
        float* Pt = (float*)d_ws;
        dim3 g2(B / 64, OUT / 64, 4);
        k2_partial<<<g2, 256, 0, stream>>>(spikes, W2, Pt, B, OUT, H, KC2);
        const int total4 = (B * OUT) / 4;
        k2_combine<<<(total4 + 255) / 256, 256, 0, stream>>>(
            Pt, b2, out, OUT, total4, (size_t)B * OUT / 4);
    } else {
        dim3 g2(B / 64, OUT / 64);
        k2_gemm<<<g2, 256, 0, stream>>>(spikes, W2, b2, out, B, OUT, H);
    }
}

// Round 7
// 416.514 us; speedup vs baseline: 1.1545x; 1.1545x over previous
//
#include <hip/hip_runtime.h>
#include <hip/hip_bf16.h>
#include <stdint.h>

typedef __attribute__((ext_vector_type(8))) short bf16x8;
typedef __attribute__((ext_vector_type(4))) float f32x4;

// Contraction-proof single f32 ops (np emulation must stay unfused).
__device__ __forceinline__ float vmulf(float a, float b) {
    float d; asm volatile("v_mul_f32 %0, %1, %2" : "=v"(d) : "v"(a), "v"(b)); return d;
}
__device__ __forceinline__ float vaddf(float a, float b) {
    float d; asm volatile("v_add_f32 %0, %1, %2" : "=v"(d) : "v"(a), "v"(b)); return d;
}
__device__ __forceinline__ float vsubf(float a, float b) {
    float d; asm volatile("v_sub_f32 %0, %1, %2" : "=v"(d) : "v"(a), "v"(b)); return d;
}

__device__ __forceinline__ short bf16h(float v) {
    __hip_bfloat16 h = __float2bfloat16(v);
    return *(short*)&h;
}
__device__ __forceinline__ float bf16f(short s) {
    return __uint_as_float(((unsigned int)(unsigned short)s) << 16);
}
__device__ __forceinline__ void split2(float v, short& h, short& m) {
    h = bf16h(v);
    m = bf16h(__fsub_rn(v, bf16f(h)));
}

__device__ __forceinline__ float decode_scalar(const void* p, float dflt) {
    float f = *(const float*)p;
    if (!(f == f) || fabsf(f) > 1.0e6f) return dflt;
    return f;
}
__device__ __forceinline__ int decode_ts(const void* p) {
    int w = *(const int*)p;
    if (w >= 1 && w <= 100000) return w;
    return 32;
}

// global->LDS DMA, 16B per lane, zero staging VGPRs. LDS dest is
// wave-uniform base + lane*16 (linear); size must be a literal.
__device__ __forceinline__ void gl16(const float* g, float* l) {
    __builtin_amdgcn_global_load_lds(
        (const __attribute__((address_space(1))) unsigned int*)g,
        (__attribute__((address_space(3))) unsigned int*)l, 16, 0, 0);
}

#define LDA 36   // LDS row stride for the FALLBACK kernels (padded, verified)

// -------- k1a: one BLIS KC=512 panel per block (exact ascending-k chain) ----
// Reference (VERIFIED R17-R19) = AOCL-BLIS zen sgemm: exact KC=512 panels,
// sequential ascending-k IEEE-FMA chain per C element, C = P0 + P1 in order.
// R26 = R25 with the COVERAGE BUG fixed: R25 staged only rows 0..63 (one
//   1 KB gl16/wave = 16 of the 64 B rows; 4 waves = 64 rows) -> rows 64..127
//   were garbage, absmax 42.7. Now each wave stages 32 rows per array via
//   TWO gl16 calls (bases 32w and 32w+16). Schedule itself (gl16 + one
//   barrier per chunk, dbuf) was PROVEN bit-exact in R5 (absmax 0.0078125).
// Structure: BK=16 dbuf, As/Bs[2][128][16] = 32 KB total -> 4 blocks/CU
//   (R5 lesson: 64 KB dbuf halved occupancy; register prefetch spills:
//   R21/R22/R23). Per chunk: barrier (own-wave vmcnt drain => DMA(c)
//   landed; all waves done reading buf d^1); issue DMA(c+1) -> buf d^1;
//   compute chunk c from buf d. DMA has the whole ~2048-cyc FMA phase.
// Swizzle (both-sides, rule T21), 16-float rows, 4-float slots: physical
//   slot s of row r holds logical slot s ^ ((r>>1)&3). DMA writes linearly
//   -> source elem pre-swizzled: lane l loads elem ((l&3)^((l>>3)&3))*4
//   ((row>>1)&3 == (l>>3)&3 since 32w,16c2 are 0 mod 4 after >>1).
//   Reads: col = (g ^ ((ty or tx)>>1)&3)*4 (i/j-independent: 16i,16j drop
//   out mod 4). Banks: af 2-way + 16-wide broadcast, bf 2-way (free, m136).
// Numerics: same floats at permuted slots; per-element FMA chain ascending
//   k (chunk->g->kk) -> bit-identical (absmax must stay 0.0078125).
__global__ __launch_bounds__(256) void k1_panel_gemm(
    const float* __restrict__ X,    // [M,K] fp32
    const float* __restrict__ W1,   // [N,K] fp32
    float* __restrict__ P0,         // [M,N] panel-0 out (spikes buffer)
    float* __restrict__ P1,         // [M,N] panel-1 out (workspace)
    int M, int N, int K, int KC)
{
    __shared__ __align__(16) float As[2][128][16];   // 16 KB
    __shared__ __align__(16) float Bs[2][128][16];   // 16 KB

    const int t  = threadIdx.x;
    const int tx = t & 15;
    const int ty = t >> 4;
    const int m0 = blockIdx.x * 128;
    const int n0 = blockIdx.y * 128;
    const int kz = blockIdx.z * KC;
    float* __restrict__ Pout = blockIdx.z ? P1 : P0;

    float p[8][8] = {};   // this panel's sequential chain

    // staging: wave w stages rows 32w..32w+31 of As and Bs via TWO 1 KB
    // DMAs per array (16 rows each). lane l -> row base + (l>>2), physical
    // slot l&3; source elem pre-swizzled so the linear DMA write lands the
    // swizzled layout.
    const int w     = t >> 6;
    const int l     = t & 63;
    const int r0    = 32 * w + (l >> 2);          // rows 32w..32w+15
    const int r1    = r0 + 16;                    // rows 32w+16..32w+31
    const int selem = ((l & 3) ^ ((l >> 3) & 3)) << 2;
    const int oa0 = (m0 + r0) * K + selem;
    const int oa1 = (m0 + r1) * K + selem;
    const int ob0 = (n0 + r0) * K + selem;
    const int ob1 = (n0 + r1) * K + selem;

    // prologue: chunk 0 -> buffer 0
    gl16(X  + oa0 + kz, &As[0][32 * w][0]);
    gl16(X  + oa1 + kz, &As[0][32 * w + 16][0]);
    gl16(W1 + ob0 + kz, &Bs[0][32 * w][0]);
    gl16(W1 + ob1 + kz, &Bs[0][32 * w + 16][0]);

    const int cax = (ty >> 1) & 3;   // read-side xor group for af rows
    const int cbx = (tx >> 1) & 3;   // read-side xor group for bf rows

    const int nch = KC >> 4;         // 32 chunks of BK=16
    for (int c = 0; c < nch; ++c) {
        __syncthreads();             // DMA(c) drained; buf d^1 reads done
        const int d = c & 1;
        if (c + 1 < nch) {
            const int kn = kz + ((c + 1) << 4);
            const int dn = d ^ 1;
            gl16(X  + oa0 + kn, &As[dn][32 * w][0]);
            gl16(X  + oa1 + kn, &As[dn][32 * w + 16][0]);
            gl16(W1 + ob0 + kn, &Bs[dn][32 * w][0]);
            gl16(W1 + ob1 + kn, &Bs[dn][32 * w + 16][0]);
        }
        #pragma unroll
        for (int g = 0; g < 4; ++g) {
            float4 bfv[8];
            const int cb = (g ^ cbx) << 2;
            #pragma unroll
            for (int j = 0; j < 8; ++j)
                bfv[j] = *(const float4*)&Bs[d][tx + 16 * j][cb];
            const int ca = (g ^ cax) << 2;
            #pragma unroll
            for (int i = 0; i < 8; ++i) {
                const float4 af = *(const float4*)&As[d][ty + 16 * i][ca];
                #pragma unroll
                for (int kk = 0; kk < 4; ++kk) {
                    const float a = ((const float*)&af)[kk];
                    #pragma unroll
                    for (int j = 0; j < 8; ++j)
                        p[i][j] = __builtin_fmaf(a, ((const float*)&bfv[j])[kk], p[i][j]);
                }
            }
        }
    }

    #pragma unroll
    for (int i = 0; i < 8; ++i) {
        const size_t rowb = (size_t)(m0 + ty + 16 * i) * N;
        #pragma unroll
        for (int j = 0; j < 8; ++j)
            Pout[rowb + n0 + tx + 16 * j] = p[i][j];
    }
}

// -------- k1b: fold c = P0 + P1 (BLIS order) + exact f32 asm-unfused scan ---
__global__ __launch_bounds__(256) void k1_combine_scan(
    const float* __restrict__ P0,
    const float* __restrict__ P1,
    const float* __restrict__ b1,
    const void* tau_mem_p, const void* tau_syn_p,
    const void* v_thresh_p, const void* v_reset_p, const void* ts_p,
    float* __restrict__ spikes, int N, int total4)
{
    const int idx4 = blockIdx.x * 256 + threadIdx.x;
    if (idx4 >= total4) return;

    const float tau_m = decode_scalar(tau_mem_p, 10.0f);
    const float tau_s = decode_scalar(tau_syn_p, 5.0f);
    const float vth   = decode_scalar(v_thresh_p, 1.0f);
    const float vrs   = decode_scalar(v_reset_p, 0.0f);
    const int   ts    = decode_ts(ts_p);
    const float rs    = 1.0f / tau_s;
    const float rm    = 1.0f / tau_m;
    const float ivts  = 1.0f / (float)ts;

    const float4 a = ((const float4*)P0)[idx4];
    const float4 b = ((const float4*)P1)[idx4];
    const int col0 = (idx4 * 4) % N;
    const float4 bb = *(const float4*)&b1[col0];

    float cur[4], iv[4], vv[4], cnt[4];
    const float av[4] = {a.x, a.y, a.z, a.w};
    const float bv[4] = {b.x, b.y, b.z, b.w};
    const float bbv[4] = {bb.x, bb.y, bb.z, bb.w};
    #pragma unroll
    for (int e = 0; e < 4; ++e) {
        const float c = vaddf(av[e], bv[e]);         // BLIS fold: P0 + P1
        cur[e] = vmulf(vaddf(c, bbv[e]), ivts);      // exact /32
        iv[e] = 0.0f; vv[e] = 0.0f; cnt[e] = 0.0f;
    }
    for (int tt = 0; tt < ts; ++tt) {
        #pragma unroll
        for (int e = 0; e < 4; ++e) {
            iv[e] = vaddf(vsubf(iv[e], vmulf(rs, iv[e])), cur[e]);
            vv[e] = vaddf(vsubf(vv[e], vmulf(rm, vv[e])), iv[e]);
            const bool s = (vv[e] >= vth);
            cnt[e] += s ? 1.0f : 0.0f;
            vv[e]   = s ? vrs : vv[e];
        }
    }
    ((float4*)spikes)[idx4] = make_float4(cnt[0], cnt[1], cnt[2], cnt[3]);
}

// -------- fallback k1 (R18, verified): used when ws_size is too small -------
__global__ __launch_bounds__(256) void k1_f32chain_snn(
    const float* __restrict__ X, const float* __restrict__ W1,
    const float* __restrict__ b1,
    const void* tau_mem_p, const void* tau_syn_p,
    const void* v_thresh_p, const void* v_reset_p, const void* ts_p,
    float* __restrict__ spikes, int M, int N, int K, int f0)
{
    __shared__ float As[128][LDA];
    __shared__ float Bs[128][LDA];

    const int t  = threadIdx.x;
    const int tx = t & 15;
    const int ty = t >> 4;
    const int m0 = blockIdx.x * 128;
    const int n0 = blockIdx.y * 128;

    float c[8][8] = {};
    float p[8][8] = {};

    for (int k0 = 0; k0 < K; k0 += 32) {
        #pragma unroll
        for (int cc = 0; cc < 4; ++cc) {
            const int li  = cc * 256 + t;
            const int row = li >> 3;
            const int q   = li & 7;
            *(float4*)&As[row][q * 4] =
                *(const float4*)&X[(size_t)(m0 + row) * K + k0 + q * 4];
            *(float4*)&Bs[row][q * 4] =
                *(const float4*)&W1[(size_t)(n0 + row) * K + k0 + q * 4];
        }
        __syncthreads();
        #pragma unroll
        for (int g = 0; g < 8; ++g) {
            float4 af[8], bf[8];
            #pragma unroll
            for (int i = 0; i < 8; ++i)
                af[i] = *(const float4*)&As[ty + 16 * i][g * 4];
            #pragma unroll
            for (int j = 0; j < 8; ++j)
                bf[j] = *(const float4*)&Bs[tx + 16 * j][g * 4];
            #pragma unroll
            for (int kk = 0; kk < 4; ++kk) {
                #pragma unroll
                for (int i = 0; i < 8; ++i) {
                    const float a = ((const float*)&af[i])[kk];
                    #pragma unroll
                    for (int j = 0; j < 8; ++j)
                        p[i][j] = __builtin_fmaf(a, ((const float*)&bf[j])[kk], p[i][j]);
                }
            }
        }
        __syncthreads();
        const int ke = k0 + 32;
        if (ke == f0 || ke == K) {
            #pragma unroll
            for (int i = 0; i < 8; ++i)
                #pragma unroll
                for (int j = 0; j < 8; ++j) {
                    c[i][j] = vaddf(c[i][j], p[i][j]);
                    p[i][j] = 0.0f;
                }
        }
    }

    const float tau_m = decode_scalar(tau_mem_p, 10.0f);
    const float tau_s = decode_scalar(tau_syn_p, 5.0f);
    const float vth   = decode_scalar(v_thresh_p, 1.0f);
    const float vrs   = decode_scalar(v_reset_p, 0.0f);
    const int   ts    = decode_ts(ts_p);
    const float rs    = 1.0f / tau_s;
    const float rm    = 1.0f / tau_m;
    const float ivts  = 1.0f / (float)ts;

    #pragma unroll
    for (int j = 0; j < 8; ++j) {
        const int col    = n0 + tx + 16 * j;
        const float bias = b1[col];
        float cur[8], iv[8], vv[8], cnt[8];
        #pragma unroll
        for (int i = 0; i < 8; ++i) {
            cur[i] = vmulf(vaddf(c[i][j], bias), ivts);
            iv[i] = 0.0f; vv[i] = 0.0f; cnt[i] = 0.0f;
        }
        for (int tt = 0; tt < ts; ++tt) {
            #pragma unroll
            for (int i = 0; i < 8; ++i) {
                iv[i] = vaddf(vsubf(iv[i], vmulf(rs, iv[i])), cur[i]);
                vv[i] = vaddf(vsubf(vv[i], vmulf(rm, vv[i])), iv[i]);
                const bool s = (vv[i] >= vth);
                cnt[i] += s ? 1.0f : 0.0f;
                vv[i]   = s ? vrs : vv[i];
            }
        }
        #pragma unroll
        for (int i = 0; i < 8; ++i)
            spikes[(size_t)(m0 + ty + 16 * i) * N + col] = cnt[i];
    }
}

// -------- k2a: split-K partial GEMM (MFMA bf16-split), no bias --------------
// z selects a KC2=512 k-range; partial -> Pt[z]. 1024 blocks = 4/CU (vs the
// old full-K k2's 256 = 1/CU, which was latency-bound at ~100+ us).
__global__ __launch_bounds__(256) void k2_partial(
    const float* __restrict__ S, const float* __restrict__ W2,
    float* __restrict__ Pt,      // [4][M,N2] partials
    int M, int N2, int K2, int KC2)
{
    __shared__ __align__(16) short Sa[64 * 32];
    __shared__ __align__(16) short Bh[64 * 32];
    __shared__ __align__(16) short Bm[64 * 32];

    const int t    = threadIdx.x;
    const int l    = t & 63;
    const int w    = t >> 6;
    const int quad = l >> 4;
    const int r    = l & 15;
    const int wm   = w & 1;
    const int wn   = w >> 1;

    const int m0 = blockIdx.x * 64;
    const int n0 = blockIdx.y * 64;
    const int kz = blockIdx.z * KC2;
    float* __restrict__ outp = Pt + (size_t)blockIdx.z * M * N2;

    f32x4 acc[2][2] = {};

    for (int k0 = kz; k0 < kz + KC2; k0 += 32) {
        #pragma unroll
        for (int cc = 0; cc < 2; ++cc) {
            const int li  = cc * 256 + t;
            const int row = li >> 3;
            const int q   = li & 7;
            const float4 vs = *(const float4*)&S[(size_t)(m0 + row) * K2 + k0 + q * 4];
            *(short4*)&Sa[row * 32 + q * 4] =
                make_short4(bf16h(vs.x), bf16h(vs.y), bf16h(vs.z), bf16h(vs.w));
            const float4 vb = *(const float4*)&W2[(size_t)(n0 + row) * K2 + k0 + q * 4];
            short h[4], m_[4];
            split2(vb.x, h[0], m_[0]); split2(vb.y, h[1], m_[1]);
            split2(vb.z, h[2], m_[2]); split2(vb.w, h[3], m_[3]);
            *(short4*)&Bh[row * 32 + q * 4] = make_short4(h[0], h[1], h[2], h[3]);
            *(short4*)&Bm[row * 32 + q * 4] = make_short4(m_[0], m_[1], m_[2], m_[3]);
        }
        __syncthreads();

        bf16x8 af[2], bh[2], bm[2];
        #pragma unroll
        for (int i = 0; i < 2; ++i) {
            af[i] = *(const bf16x8*)&Sa[(wm * 32 + i * 16 + r) * 32 + quad * 8];
            bh[i] = *(const bf16x8*)&Bh[(wn * 32 + i * 16 + r) * 32 + quad * 8];
            bm[i] = *(const bf16x8*)&Bm[(wn * 32 + i * 16 + r) * 32 + quad * 8];
        }
        #pragma unroll
        for (int i = 0; i < 2; ++i)
            #pragma unroll
            for (int j = 0; j < 2; ++j) {
                acc[i][j] = __builtin_amdgcn_mfma_f32_16x16x32_bf16(af[i], bh[j], acc[i][j], 0, 0, 0);
                acc[i][j] = __builtin_amdgcn_mfma_f32_16x16x32_bf16(af[i], bm[j], acc[i][j], 0, 0, 0);
            }
        __syncthreads();
    }

    #pragma unroll
    for (int j = 0; j < 2; ++j) {
        const int col = n0 + wn * 32 + j * 16 + r;
        #pragma unroll
        for (int i = 0; i < 2; ++i) {
            const int rowb = m0 + wm * 32 + i * 16 + quad * 4;
            #pragma unroll
            for (int e = 0; e < 4; ++e)
                outp[(size_t)(rowb + e) * N2 + col] = acc[i][j][e];
        }
    }
}

// -------- k2b: out = p0+p1+p2+p3 + b2 ---------------------------------------
__global__ __launch_bounds__(256) void k2_combine(
    const float* __restrict__ Pt, const float* __restrict__ b2,
    float* __restrict__ out, int N2, int total4, size_t stride4)
{
    const int idx4 = blockIdx.x * 256 + threadIdx.x;
    if (idx4 >= total4) return;
    float4 s = ((const float4*)Pt)[idx4];
    #pragma unroll
    for (int z = 1; z < 4; ++z) {
        const float4 v = ((const float4*)Pt)[stride4 * z + idx4];
        s.x += v.x; s.y += v.y; s.z += v.z; s.w += v.w;
    }
    const float4 bb = *(const float4*)&b2[(idx4 * 4) % N2];
    s.x += bb.x; s.y += bb.y; s.z += bb.z; s.w += bb.w;
    ((float4*)out)[idx4] = s;
}

// -------- fallback k2 (verified R4-R19): full-K, bias fused -----------------
__global__ __launch_bounds__(256) void k2_gemm(
    const float* __restrict__ S, const float* __restrict__ W2,
    const float* __restrict__ b2, float* __restrict__ out,
    int M, int N2, int K2)
{
    __shared__ __align__(16) short Sa[64 * 32];
    __shared__ __align__(16) short Bh[64 * 32];
    __shared__ __align__(16) short Bm[64 * 32];

    const int t    = threadIdx.x;
    const int l    = t & 63;
    const int w    = t >> 6;
    const int quad = l >> 4;
    const int r    = l & 15;
    const int wm   = w & 1;
    const int wn   = w >> 1;

    const int m0 = blockIdx.x * 64;
    const int n0 = blockIdx.y * 64;

    f32x4 acc[2][2] = {};

    for (int k0 = 0; k0 < K2; k0 += 32) {
        #pragma unroll
        for (int cc = 0; cc < 2; ++cc) {
            const int li  = cc * 256 + t;
            const int row = li >> 3;
            const int q   = li & 7;
            const float4 vs = *(const float4*)&S[(size_t)(m0 + row) * K2 + k0 + q * 4];
            *(short4*)&Sa[row * 32 + q * 4] =
                make_short4(bf16h(vs.x), bf16h(vs.y), bf16h(vs.z), bf16h(vs.w));
            const float4 vb = *(const float4*)&W2[(size_t)(n0 + row) * K2 + k0 + q * 4];
            short h[4], m_[4];
            split2(vb.x, h[0], m_[0]); split2(vb.y, h[1], m_[1]);
            split2(vb.z, h[2], m_[2]); split2(vb.w, h[3], m_[3]);
            *(short4*)&Bh[row * 32 + q * 4] = make_short4(h[0], h[1], h[2], h[3]);
            *(short4*)&Bm[row * 32 + q * 4] = make_short4(m_[0], m_[1], m_[2], m_[3]);
        }
        __syncthreads();

        bf16x8 af[2], bh[2], bm[2];
        #pragma unroll
        for (int i = 0; i < 2; ++i) {
            af[i] = *(const bf16x8*)&Sa[(wm * 32 + i * 16 + r) * 32 + quad * 8];
            bh[i] = *(const bf16x8*)&Bh[(wn * 32 + i * 16 + r) * 32 + quad * 8];
            bm[i] = *(const bf16x8*)&Bm[(wn * 32 + i * 16 + r) * 32 + quad * 8];
        }
        #pragma unroll
        for (int i = 0; i < 2; ++i)
            #pragma unroll
            for (int j = 0; j < 2; ++j) {
                acc[i][j] = __builtin_amdgcn_mfma_f32_16x16x32_bf16(af[i], bh[j], acc[i][j], 0, 0, 0);
                acc[i][j] = __builtin_amdgcn_mfma_f32_16x16x32_bf16(af[i], bm[j], acc[i][j], 0, 0, 0);
            }
        __syncthreads();
    }

    #pragma unroll
    for (int j = 0; j < 2; ++j) {
        const int col = n0 + wn * 32 + j * 16 + r;
        const float bias = b2[col];
        #pragma unroll
        for (int i = 0; i < 2; ++i) {
            const int rowb = m0 + wm * 32 + i * 16 + quad * 4;
            #pragma unroll
            for (int e = 0; e < 4; ++e)
                out[(size_t)(rowb + e) * N2 + col] = __fadd_rn(acc[i][j][e], bias);
        }
    }
}

extern "C" void kernel_launch(void* const* d_in, const int* in_sizes, int n_in,
                              void* d_out, int out_size, void* d_ws, size_t ws_size,
                              hipStream_t stream) {
    (void)n_in; (void)out_size;

    const float* X  = (const float*)d_in[0];
    const float* W1 = (const float*)d_in[1];
    const float* b1 = (const float*)d_in[2];
    const float* W2 = (const float*)d_in[3];
    const float* b2 = (const float*)d_in[4];
    const void* tau_mem = d_in[5];
    const void* tau_syn = d_in[6];
    const void* vth     = d_in[7];
    const void* vrs     = d_in[8];
    const void* ts      = d_in[11];

    const int H   = in_sizes[2];             // 2048
    const int IN  = in_sizes[1] / H;         // 1024
    const int OUT = in_sizes[4];             // 256
    const int B   = in_sizes[0] / IN;        // 4096

    float* out    = (float*)d_out;           // [B, OUT] fp32
    float* spikes = out + (size_t)B * OUT;   // [B, H]  fp32

    const int KC = 512;                      // VERIFIED: AOCL-BLIS zen KC
    const size_t panel_bytes = (size_t)B * H * sizeof(float);
    const bool ws_ok = (IN == 2 * KC) && (ws_size >= panel_bytes) &&
                       ((uintptr_t)d_ws % 16 == 0);

    if (ws_ok) {
        float* P1 = (float*)d_ws;
        dim3 g1(B / 128, H / 128, 2);
        k1_panel_gemm<<<g1, 256, 0, stream>>>(X, W1, spikes, P1, B, H, IN, KC);

        const int total4 = (B * H) / 4;
        k1_combine_scan<<<(total4 + 255) / 256, 256, 0, stream>>>(
            spikes, P1, b1, tau_mem, tau_syn, vth, vrs, ts, spikes, H, total4);
    } else {
        dim3 g1(B / 128, H / 128);
        k1_f32chain_snn<<<g1, 256, 0, stream>>>(X, W1, b1, tau_mem, tau_syn, vth, vrs, ts,
                                                spikes, B, H, IN, KC);
    }

    // k2: split-K z=4 partials into d_ws (free after combine_scan; 16 MB),
    // then tiny combine. Falls back to full-K k2 if ws not usable.
    const int KC2 = 512;
    const size_t k2_part_bytes = 4 * (size_t)B * OUT * sizeof(float);
    if (ws_ok && H == 4 * KC2 && ws_size >= k2_part_bytes) {
        float* Pt = (float*)d_ws;
        dim3 g2(B / 64, OUT / 64, 4);
        k2_partial<<<g2, 256, 0, stream>>>(spikes, W2, Pt, B, OUT, H, KC2);
        const int total4 = (B * OUT) / 4;
        k2_combine<<<(total4 + 255) / 256, 256, 0, stream>>>(
            Pt, b2, out, OUT, total4, (size_t)B * OUT / 4);
    } else {
        dim3 g2(B / 64, OUT / 64);
        k2_gemm<<<g2, 256, 0, stream>>>(spikes, W2, b2, out, B, OUT, H);
    }
}